// Round 4
// baseline (134.117 us; speedup 1.0000x reference)
//
#include <hip/hip_runtime.h>
#include <stdint.h>

// Problem constants (fixed by reference)
#define NTOK 8192
#define DM   1024
#define NE   8
#define NR   16
#define KX   1152   // DM + NE*NR = 1024 + 128

typedef short bf16x8 __attribute__((ext_vector_type(8)));
typedef float f32x4  __attribute__((ext_vector_type(4)));

__device__ __forceinline__ unsigned short f2bf(float f) {
    union { float f; unsigned u; } v; v.f = f;
    unsigned r = v.u + 0x7fffu + ((v.u >> 16) & 1u);   // RNE
    return (unsigned short)(r >> 16);
}

__device__ __forceinline__ void gld16(const void* g, void* l) {
    __builtin_amdgcn_global_load_lds((__attribute__((address_space(1))) void*)g,
                                     (__attribute__((address_space(3))) void*)l,
                                     16, 0, 0);
}

#define VM_WAIT(n) asm volatile("s_waitcnt vmcnt(" #n ")" ::: "memory")
#define BAR() __builtin_amdgcn_s_barrier()

// ---------------------------------------------------------------------------
// prep: fused role-by-block kernel (R0-proven, 128.5us config — unchanged).
//  blocks [0,2048):     fp32 gating (wave/token) + x -> bf16 into Xext[:,0:1024]
//  blocks [2048,3072):  WBext[j][0:1152] = [W_base[j][:] | B[:, j]]  (bf16)
//  blocks [3072,3200):  At[p][0:1024] = A[e][:][r] transpose        (bf16)
// ---------------------------------------------------------------------------
__global__ __launch_bounds__(256) void prep(const float* __restrict__ x,
                                            const float* __restrict__ Wg,
                                            const float* __restrict__ Asrc,
                                            const float* __restrict__ Bsrc,
                                            const float* __restrict__ Wb,
                                            float* __restrict__ combine,
                                            unsigned short* __restrict__ Xext,
                                            unsigned short* __restrict__ WBext,
                                            unsigned short* __restrict__ At) {
    const int b = blockIdx.x;
    const int t = threadIdx.x;

    if (b < 2048) {
        const int lane = t & 63;
        const int w = t >> 6;
        const int n = b * 4 + w;

        const float4* x4 = (const float4*)(x + (size_t)n * DM);
        float4 xv[4];
        #pragma unroll
        for (int i = 0; i < 4; ++i) xv[i] = x4[i * 64 + lane];

        float acc[NE];
        #pragma unroll
        for (int e = 0; e < NE; ++e) {
            const float4* wg4 = (const float4*)(Wg + (size_t)e * DM);
            float s = 0.f;
            #pragma unroll
            for (int i = 0; i < 4; ++i) {
                float4 g = wg4[i * 64 + lane];
                s += xv[i].x * g.x + xv[i].y * g.y + xv[i].z * g.z + xv[i].w * g.w;
            }
            acc[e] = s;
        }
        #pragma unroll
        for (int off = 32; off >= 1; off >>= 1) {
            #pragma unroll
            for (int e = 0; e < NE; ++e) acc[e] += __shfl_xor(acc[e], off, 64);
        }
        // top-2, lowest index wins ties (matches lax.top_k)
        float best = acc[0]; int bi = 0;
        #pragma unroll
        for (int e = 1; e < NE; ++e) if (acc[e] > best) { best = acc[e]; bi = e; }
        float sec = -1e30f; int si = 0;
        #pragma unroll
        for (int e = 0; e < NE; ++e) if (e != bi && acc[e] > sec) { sec = acc[e]; si = e; }
        const float ed = __expf(sec - best);
        const float w0 = 1.f / (1.f + ed);
        const float w1 = ed * w0;
        if (lane < NE)
            combine[n * NE + lane] = (lane == bi) ? w0 : ((lane == si) ? w1 : 0.f);

        unsigned short* xrow = Xext + (size_t)n * KX;
        #pragma unroll
        for (int i = 0; i < 4; ++i) {
            ushort4 o;
            o.x = f2bf(xv[i].x); o.y = f2bf(xv[i].y);
            o.z = f2bf(xv[i].z); o.w = f2bf(xv[i].w);
            *(ushort4*)(xrow + (i * 64 + lane) * 4) = o;
        }
    } else if (b < 3072) {
        const int j = b - 2048;
        unsigned short* row = WBext + (size_t)j * KX;
        float4 v = ((const float4*)(Wb + (size_t)j * DM))[t];
        ushort4 o;
        o.x = f2bf(v.x); o.y = f2bf(v.y); o.z = f2bf(v.z); o.w = f2bf(v.w);
        *(ushort4*)(row + t * 4) = o;
        if (t < 128) row[DM + t] = f2bf(Bsrc[(size_t)t * DM + j]);   // B[e][r][j]
    } else {
        const int p = b - 3072;
        const int e = p >> 4, r = p & 15;
        for (int d = t; d < DM; d += 256)
            At[(size_t)p * DM + d] = f2bf(Asrc[e * (DM * NR) + d * NR + r]);
    }
}

// ---------------------------------------------------------------------------
// hall: Hfull = (x_bf16 @ At^T) * combine -> bf16 into Xext[:, 1024:1152]
//   512 blocks (32 tokens x 64 cols -> 2 blocks/CU), single-barrier
//   double-buffered K-loop (R0-proven, 128.5us config — unchanged).
// ---------------------------------------------------------------------------
__global__ __launch_bounds__(256) void hall_kernel(unsigned short* Xext,
                                                   const unsigned short* __restrict__ At,
                                                   const float* __restrict__ combine) {
    // per buffer: xt 32x64 bf16 (4 KB) + at 64x64 bf16 (8 KB) = 12 KB; x2 = 24 KB
    __shared__ __align__(16) unsigned short lds[12288];
    const int t = threadIdx.x;
    const int lane = t & 63;
    const int w = t >> 6;
    const int quad = lane >> 4;
    const int l15 = lane & 15;
    const int bid = blockIdx.x;        // 512
    const int bm = bid >> 1;           // token tile 0..255
    const int cb = bid & 1;            // column half 0..1
    const int n0 = bm * 32;
    const int wm = (w & 1) * 16;
    const int wn = (w >> 1) * 32;

    const int srow = t >> 3;                     // 0..31
    const int seg  = (t & 7) ^ (srow & 7);       // XOR swizzle (global side)

    const unsigned short* gX  = Xext + (size_t)(n0 + srow) * KX + seg * 8;
    const unsigned short* gA0 = At + (size_t)(cb * 64 + srow) * DM + seg * 8;
    const unsigned short* gA1 = At + (size_t)(cb * 64 + 32 + srow) * DM + seg * 8;

    f32x4 acc[2] = {};

    #define HALL_STAGE(k0, s)                                              \
        gld16(gX  + (k0), (char*)lds + (s) * 12288 + w * 1024);            \
        gld16(gA0 + (k0), (char*)lds + (s) * 12288 + 4096 + w * 1024);     \
        gld16(gA1 + (k0), (char*)lds + (s) * 12288 + 8192 + w * 1024);

    #define HALL_COMPUTE(s)                                                        \
        {                                                                          \
            const int xo = (s) * 6144, ao = (s) * 6144 + 2048;                     \
            _Pragma("unroll")                                                      \
            for (int kk = 0; kk < 2; ++kk) {                                       \
                const int gs = kk * 4 + quad;                                      \
                const int sw = (gs ^ (l15 & 7)) * 8;                               \
                bf16x8 a = *(const bf16x8*)&lds[xo + (wm + l15) * 64 + sw];        \
                _Pragma("unroll")                                                  \
                for (int jf = 0; jf < 2; ++jf) {                                   \
                    bf16x8 bb = *(const bf16x8*)&lds[ao + (wn + jf * 16 + l15) * 64 + sw]; \
                    acc[jf] = __builtin_amdgcn_mfma_f32_16x16x32_bf16(a, bb, acc[jf], 0, 0, 0); \
                }                                                                  \
            }                                                                      \
        }

    HALL_STAGE(0, 0);
    for (int k0 = 0; k0 < DM; k0 += 128) {       // 8 macro-iters (16 chunks)
        __syncthreads();
        HALL_STAGE(k0 + 64, 1);
        HALL_COMPUTE(0);
        __syncthreads();
        if (k0 + 128 < DM) { HALL_STAGE(k0 + 128, 0); }
        HALL_COMPUTE(1);
    }

    // Epilogue: scale by combine, write bf16 H
    #pragma unroll
    for (int jf = 0; jf < 2; ++jf) {
        const int p = cb * 64 + wn + jf * 16 + l15;
        const int e = p >> 4;
        #pragma unroll
        for (int v = 0; v < 4; ++v) {
            const int n = n0 + wm + quad * 4 + v;
            const float val = acc[jf][v] * combine[n * NE + e];
            Xext[(size_t)n * KX + DM + p] = f2bf(val);
        }
    }
    #undef HALL_STAGE
    #undef HALL_COMPUTE
}

// ---------------------------------------------------------------------------
// mgemm2 (R4): out[8192][1024] = Xext[8192][1152] @ WBext[1024][1152]^T + bias
//   256x128 tile, 512 threads (8 waves, 4M x 2N, per-wave 64x64 = same proven
//   fragment math), BK=64 double-buffered: 96 KB LDS -> 1 block/CU,
//   2 waves/SIMD. Deep-buffer chunk schedule (the 8-wave regime where
//   counted-vmcnt/setprio actually pay):
//     vmcnt(6) -> bar -> 16x ds_read_b128 to regs -> lgkmcnt(0)+schedbar
//     -> bar -> issue next 6-load stage -> setprio(1) 32 MFMA setprio(0)
//   Stage has a full chunk in flight; MFMA cluster is pure-reg so the
//   co-resident wave's loads interleave under it. XCD swizzle keeps each
//   A-panel's 8 bn-blocks on one XCD.
// ---------------------------------------------------------------------------
__global__ __launch_bounds__(512, 2) void mgemm2(const unsigned short* __restrict__ Xext,
                                                 const unsigned short* __restrict__ WBext,
                                                 const float* __restrict__ bias,
                                                 float* __restrict__ out) {
    __shared__ __align__(16) unsigned short lds[49152];   // 96 KB (2 x 48 KB)
    const int t = threadIdx.x;           // 0..511
    const int lane = t & 63;
    const int w = t >> 6;                // 0..7
    const int quad = lane >> 4;
    const int l15 = lane & 15;

    const int bid = blockIdx.x;          // 256
    const int xcd = bid & 7;
    const int loc = bid >> 3;            // 0..31
    const int bm = xcd * 4 + (loc & 3);  // 0..31 (A-panel local to one XCD)
    const int bn = loc >> 2;             // 0..7

    const int wm = (w & 3) * 64;         // wave A-row offset within 256
    const int wn = (w >> 2) * 64;        // wave out-col offset within 128

    f32x4 acc[4][4] = {};

    // staging decomposition: each wave's 64 lanes write 1024 B = 8 rows x 128 B
    const int rbase = w * 8 + (lane >> 3);          // 0..63
    const int sseg  = (lane & 7) ^ (lane >> 3);     // XOR swizzle (global side)
    const unsigned short* gA = Xext  + (size_t)(bm * 256 + rbase) * KX + sseg * 8;
    const unsigned short* gB = WBext + (size_t)(bn * 128 + rbase) * KX + sseg * 8;

    // stage(k0, s): A 256x64 -> [s*48KB, +32KB), B 128x64 -> +32KB..48KB  (6 loads)
    #define MG2_STAGE(k0, s)                                                        \
        {                                                                           \
            _Pragma("unroll")                                                       \
            for (int i = 0; i < 4; ++i)                                             \
                gld16(gA + (size_t)(i * 64) * KX + (k0),                            \
                      (char*)lds + (s) * 49152 + i * 8192 + w * 1024);              \
            _Pragma("unroll")                                                       \
            for (int j = 0; j < 2; ++j)                                             \
                gld16(gB + (size_t)(j * 64) * KX + (k0),                            \
                      (char*)lds + (s) * 49152 + 32768 + j * 8192 + w * 1024);      \
        }

    bf16x8 af[2][4], bf[2][4];   // [kk][frag]

    #define MG2_LDFRAGS(s)                                                          \
        {                                                                           \
            const int ao = (s) * 24576, bo = (s) * 24576 + 16384;                   \
            _Pragma("unroll")                                                       \
            for (int kk = 0; kk < 2; ++kk) {                                        \
                const int gs = kk * 4 + quad;                                       \
                _Pragma("unroll")                                                   \
                for (int i = 0; i < 4; ++i) {                                       \
                    const int ra = wm + i * 16 + l15;                               \
                    const int rb = wn + i * 16 + l15;                               \
                    af[kk][i] = *(const bf16x8*)&lds[ao + ra * 64 + ((gs ^ (ra & 7)) * 8)]; \
                    bf[kk][i] = *(const bf16x8*)&lds[bo + rb * 64 + ((gs ^ (rb & 7)) * 8)]; \
                }                                                                   \
            }                                                                       \
        }

    #define MG2_MFMA()                                                             \
        {                                                                          \
            _Pragma("unroll")                                                      \
            for (int kk = 0; kk < 2; ++kk)                                         \
                _Pragma("unroll")                                                  \
                for (int i = 0; i < 4; ++i)                                        \
                    _Pragma("unroll")                                              \
                    for (int j = 0; j < 4; ++j)                                    \
                        acc[i][j] = __builtin_amdgcn_mfma_f32_16x16x32_bf16(af[kk][i], bf[kk][j], acc[i][j], 0, 0, 0); \
        }

    MG2_STAGE(0, 0);
    MG2_STAGE(64, 1);
    for (int k0 = 0; k0 < KX; k0 += 128) {       // 9 iters, 2 chunks each
        // ---- chunk buf0: k = k0
        VM_WAIT(6);                               // buf0's 6 landed (buf1's 6 remain)
        BAR();
        MG2_LDFRAGS(0);
        asm volatile("s_waitcnt lgkmcnt(0)" ::: "memory");
        __builtin_amdgcn_sched_barrier(0);
        BAR();                                    // all waves done reading buf0
        if (k0 + 128 < KX) MG2_STAGE(k0 + 128, 0);
        __builtin_amdgcn_s_setprio(1);
        MG2_MFMA();
        __builtin_amdgcn_s_setprio(0);
        // ---- chunk buf1: k = k0 + 64
        if (k0 + 128 < KX) { VM_WAIT(6); } else { VM_WAIT(0); }
        BAR();
        MG2_LDFRAGS(1);
        asm volatile("s_waitcnt lgkmcnt(0)" ::: "memory");
        __builtin_amdgcn_sched_barrier(0);
        BAR();                                    // all waves done reading buf1
        if (k0 + 192 < KX) MG2_STAGE(k0 + 192, 1);
        __builtin_amdgcn_s_setprio(1);
        MG2_MFMA();
        __builtin_amdgcn_s_setprio(0);
    }
    #undef MG2_STAGE
    #undef MG2_LDFRAGS
    #undef MG2_MFMA

    // Epilogue: per-wave LDS transpose in 2 passes of 32 rows (8 KB/wave,
    // 64 KB total < 96 KB). All waves passed the final read-barrier, so
    // staging LDS is dead; each wave uses only its own region.
    BAR();
    float* lf = (float*)lds + w * 2048;
    #pragma unroll
    for (int p = 0; p < 2; ++p) {
        #pragma unroll
        for (int j = 0; j < 4; ++j) {
            const float bv = bias[bn * 128 + wn + j * 16 + l15];
            #pragma unroll
            for (int ii = 0; ii < 2; ++ii) {
                const int i = p * 2 + ii;
                #pragma unroll
                for (int v = 0; v < 4; ++v) {
                    const int row_l = ii * 16 + quad * 4 + v;          // 0..31
                    const int col_s = (j * 16 + l15) ^ ((row_l & 1) << 4);
                    lf[row_l * 64 + col_s] = acc[i][j][v] + bv;
                }
            }
        }
        __builtin_amdgcn_s_waitcnt(0);
        #pragma unroll
        for (int rr = 0; rr < 8; ++rr) {
            const int row_r = rr * 4 + (lane >> 4);                    // 0..31
            const int col4  = (lane & 15) * 4;
            const int col4s = col4 ^ ((row_r & 1) << 4);
            float4 vv = *(const float4*)&lf[row_r * 64 + col4s];
            *(float4*)&out[(size_t)(bm * 256 + wm + p * 32 + row_r) * DM + bn * 128 + wn + col4] = vv;
        }
        __builtin_amdgcn_s_waitcnt(0);   // reads done before pass-2 overwrite
    }
}

// ---------------------------------------------------------------------------
extern "C" void kernel_launch(void* const* d_in, const int* in_sizes, int n_in,
                              void* d_out, int out_size, void* d_ws, size_t ws_size,
                              hipStream_t stream) {
    const float* x  = (const float*)d_in[0];   // [8192,1024]
    const float* Wg = (const float*)d_in[1];   // [8,1024]
    const float* A  = (const float*)d_in[2];   // [8,1024,16]
    const float* B  = (const float*)d_in[3];   // [8,16,1024]
    const float* Wb = (const float*)d_in[4];   // [1024,1024]
    const float* bb = (const float*)d_in[5];   // [1024]
    float* out = (float*)d_out;

    char* ws = (char*)d_ws;
    float*          combine = (float*)ws;                                   // 262144 B
    unsigned short* Xext    = (unsigned short*)(ws + 262144);               // 18874368 B
    unsigned short* WBext   = (unsigned short*)(ws + 262144 + 18874368);    // 2359296 B
    unsigned short* At      = (unsigned short*)(ws + 262144 + 18874368 + 2359296); // 262144 B

    hipLaunchKernelGGL(prep,        dim3(3200), dim3(256), 0, stream,
                       x, Wg, A, B, Wb, combine, Xext, WBext, At);
    hipLaunchKernelGGL(hall_kernel, dim3(512),  dim3(256), 0, stream, Xext, At, combine);
    hipLaunchKernelGGL(mgemm2,      dim3(256),  dim3(512), 0, stream, Xext, WBext, bb, out);
}

// Round 5
// 132.597 us; speedup vs baseline: 1.0115x; 1.0115x over previous
//
#include <hip/hip_runtime.h>
#include <stdint.h>

// Problem constants (fixed by reference)
#define NTOK 8192
#define DM   1024
#define NE   8
#define NR   16
#define KX   1152   // DM + NE*NR = 1024 + 128

typedef short bf16x8 __attribute__((ext_vector_type(8)));
typedef float f32x4  __attribute__((ext_vector_type(4)));
typedef float f32x16 __attribute__((ext_vector_type(16)));

__device__ __forceinline__ unsigned short f2bf(float f) {
    union { float f; unsigned u; } v; v.f = f;
    unsigned r = v.u + 0x7fffu + ((v.u >> 16) & 1u);   // RNE
    return (unsigned short)(r >> 16);
}

__device__ __forceinline__ void gld16(const void* g, void* l) {
    __builtin_amdgcn_global_load_lds((__attribute__((address_space(1))) void*)g,
                                     (__attribute__((address_space(3))) void*)l,
                                     16, 0, 0);
}

// ---------------------------------------------------------------------------
// prep: fused role-by-block kernel (R0-proven, 128.5us config — unchanged).
//  blocks [0,2048):     fp32 gating (wave/token) + x -> bf16 into Xext[:,0:1024]
//  blocks [2048,3072):  WBext[j][0:1152] = [W_base[j][:] | B[:, j]]  (bf16)
//  blocks [3072,3200):  At[p][0:1024] = A[e][:][r] transpose        (bf16)
// ---------------------------------------------------------------------------
__global__ __launch_bounds__(256) void prep(const float* __restrict__ x,
                                            const float* __restrict__ Wg,
                                            const float* __restrict__ Asrc,
                                            const float* __restrict__ Bsrc,
                                            const float* __restrict__ Wb,
                                            float* __restrict__ combine,
                                            unsigned short* __restrict__ Xext,
                                            unsigned short* __restrict__ WBext,
                                            unsigned short* __restrict__ At) {
    const int b = blockIdx.x;
    const int t = threadIdx.x;

    if (b < 2048) {
        const int lane = t & 63;
        const int w = t >> 6;
        const int n = b * 4 + w;

        const float4* x4 = (const float4*)(x + (size_t)n * DM);
        float4 xv[4];
        #pragma unroll
        for (int i = 0; i < 4; ++i) xv[i] = x4[i * 64 + lane];

        float acc[NE];
        #pragma unroll
        for (int e = 0; e < NE; ++e) {
            const float4* wg4 = (const float4*)(Wg + (size_t)e * DM);
            float s = 0.f;
            #pragma unroll
            for (int i = 0; i < 4; ++i) {
                float4 g = wg4[i * 64 + lane];
                s += xv[i].x * g.x + xv[i].y * g.y + xv[i].z * g.z + xv[i].w * g.w;
            }
            acc[e] = s;
        }
        #pragma unroll
        for (int off = 32; off >= 1; off >>= 1) {
            #pragma unroll
            for (int e = 0; e < NE; ++e) acc[e] += __shfl_xor(acc[e], off, 64);
        }
        // top-2, lowest index wins ties (matches lax.top_k)
        float best = acc[0]; int bi = 0;
        #pragma unroll
        for (int e = 1; e < NE; ++e) if (acc[e] > best) { best = acc[e]; bi = e; }
        float sec = -1e30f; int si = 0;
        #pragma unroll
        for (int e = 0; e < NE; ++e) if (e != bi && acc[e] > sec) { sec = acc[e]; si = e; }
        const float ed = __expf(sec - best);
        const float w0 = 1.f / (1.f + ed);
        const float w1 = ed * w0;
        if (lane < NE)
            combine[n * NE + lane] = (lane == bi) ? w0 : ((lane == si) ? w1 : 0.f);

        unsigned short* xrow = Xext + (size_t)n * KX;
        #pragma unroll
        for (int i = 0; i < 4; ++i) {
            ushort4 o;
            o.x = f2bf(xv[i].x); o.y = f2bf(xv[i].y);
            o.z = f2bf(xv[i].z); o.w = f2bf(xv[i].w);
            *(ushort4*)(xrow + (i * 64 + lane) * 4) = o;
        }
    } else if (b < 3072) {
        const int j = b - 2048;
        unsigned short* row = WBext + (size_t)j * KX;
        float4 v = ((const float4*)(Wb + (size_t)j * DM))[t];
        ushort4 o;
        o.x = f2bf(v.x); o.y = f2bf(v.y); o.z = f2bf(v.z); o.w = f2bf(v.w);
        *(ushort4*)(row + t * 4) = o;
        if (t < 128) row[DM + t] = f2bf(Bsrc[(size_t)t * DM + j]);   // B[e][r][j]
    } else {
        const int p = b - 3072;
        const int e = p >> 4, r = p & 15;
        for (int d = t; d < DM; d += 256)
            At[(size_t)p * DM + d] = f2bf(Asrc[e * (DM * NR) + d * NR + r]);
    }
}

// ---------------------------------------------------------------------------
// hall: Hfull = (x_bf16 @ At^T) * combine -> bf16 into Xext[:, 1024:1152]
//   512 blocks (32 tokens x 64 cols -> 2 blocks/CU), single-barrier
//   double-buffered K-loop (R0-proven, 128.5us config — unchanged).
// ---------------------------------------------------------------------------
__global__ __launch_bounds__(256) void hall_kernel(unsigned short* Xext,
                                                   const unsigned short* __restrict__ At,
                                                   const float* __restrict__ combine) {
    // per buffer: xt 32x64 bf16 (4 KB) + at 64x64 bf16 (8 KB) = 12 KB; x2 = 24 KB
    __shared__ __align__(16) unsigned short lds[12288];
    const int t = threadIdx.x;
    const int lane = t & 63;
    const int w = t >> 6;
    const int quad = lane >> 4;
    const int l15 = lane & 15;
    const int bid = blockIdx.x;        // 512
    const int bm = bid >> 1;           // token tile 0..255
    const int cb = bid & 1;            // column half 0..1
    const int n0 = bm * 32;
    const int wm = (w & 1) * 16;
    const int wn = (w >> 1) * 32;

    const int srow = t >> 3;                     // 0..31
    const int seg  = (t & 7) ^ (srow & 7);       // XOR swizzle (global side)

    const unsigned short* gX  = Xext + (size_t)(n0 + srow) * KX + seg * 8;
    const unsigned short* gA0 = At + (size_t)(cb * 64 + srow) * DM + seg * 8;
    const unsigned short* gA1 = At + (size_t)(cb * 64 + 32 + srow) * DM + seg * 8;

    f32x4 acc[2] = {};

    #define HALL_STAGE(k0, s)                                              \
        gld16(gX  + (k0), (char*)lds + (s) * 12288 + w * 1024);            \
        gld16(gA0 + (k0), (char*)lds + (s) * 12288 + 4096 + w * 1024);     \
        gld16(gA1 + (k0), (char*)lds + (s) * 12288 + 8192 + w * 1024);

    #define HALL_COMPUTE(s)                                                        \
        {                                                                          \
            const int xo = (s) * 6144, ao = (s) * 6144 + 2048;                     \
            _Pragma("unroll")                                                      \
            for (int kk = 0; kk < 2; ++kk) {                                       \
                const int gs = kk * 4 + quad;                                      \
                const int sw = (gs ^ (l15 & 7)) * 8;                               \
                bf16x8 a = *(const bf16x8*)&lds[xo + (wm + l15) * 64 + sw];        \
                _Pragma("unroll")                                                  \
                for (int jf = 0; jf < 2; ++jf) {                                   \
                    bf16x8 bb = *(const bf16x8*)&lds[ao + (wn + jf * 16 + l15) * 64 + sw]; \
                    acc[jf] = __builtin_amdgcn_mfma_f32_16x16x32_bf16(a, bb, acc[jf], 0, 0, 0); \
                }                                                                  \
            }                                                                      \
        }

    HALL_STAGE(0, 0);
    for (int k0 = 0; k0 < DM; k0 += 128) {       // 8 macro-iters (16 chunks)
        __syncthreads();
        HALL_STAGE(k0 + 64, 1);
        HALL_COMPUTE(0);
        __syncthreads();
        if (k0 + 128 < DM) { HALL_STAGE(k0 + 128, 0); }
        HALL_COMPUTE(1);
    }

    // Epilogue: scale by combine, write bf16 H
    #pragma unroll
    for (int jf = 0; jf < 2; ++jf) {
        const int p = cb * 64 + wn + jf * 16 + l15;
        const int e = p >> 4;
        #pragma unroll
        for (int v = 0; v < 4; ++v) {
            const int n = n0 + wm + quad * 4 + v;
            const float val = acc[jf][v] * combine[n * NE + e];
            Xext[(size_t)n * KX + DM + p] = f2bf(val);
        }
    }
    #undef HALL_STAGE
    #undef HALL_COMPUTE
}

// ---------------------------------------------------------------------------
// mgemm: out[8192][1024] = Xext[8192][1152] @ WBext[1024][1152]^T + bias
//   R5 change: 32x32x16 MFMA (2382 TF ceiling vs 2075, half the instruction
//   count) inside the UNCHANGED R0 128.5us structure: same 128x128 tile,
//   same BK=64 double-buffer, same gld16 staging + XOR swizzle, same
//   single-barrier loop, same LDS-transpose epilogue layout.
//   Layouts (HW-verified, m74/m101): A/B lane map row|col = lane&31,
//   k = 8*(lane>>5)+e; C/D col = lane&31, row = (reg&3)+8*(reg>>2)+4*(lane>>5).
// ---------------------------------------------------------------------------
__global__ __launch_bounds__(256, 2) void mgemm(const unsigned short* __restrict__ Xext,
                                                const unsigned short* __restrict__ WBext,
                                                const float* __restrict__ bias,
                                                float* __restrict__ out) {
    __shared__ __align__(16) unsigned short lds[32768];   // 64 KB
    const int t = threadIdx.x;
    const int lane = t & 63;
    const int w = t >> 6;
    const int l31 = lane & 31;
    const int hi  = lane >> 5;          // 0..1

    const int bid = blockIdx.x;          // 512
    const int xcd = bid & 7;
    const int loc = bid >> 3;
    const int bm = xcd * 8 + (loc & 7);  // 0..63
    const int bn = loc >> 3;             // 0..7

    const int wm = (w & 1) * 64;
    const int wn = (w >> 1) * 64;

    f32x16 acc[2][2] = {};               // per-wave 64x64 as 2x2 of 32x32

    const int srow = t >> 3;                     // 0..31
    const int seg  = (t & 7) ^ (srow & 7);       // XOR swizzle (global side)
    const unsigned short* gA = Xext  + (size_t)(bm * 128 + srow) * KX + seg * 8;
    const unsigned short* gB = WBext + (size_t)(bn * 128 + srow) * KX + seg * 8;

    #define MG_STAGE(k0, s)                                                          \
        _Pragma("unroll")                                                            \
        for (int c = 0; c < 4; ++c) {                                                \
            gld16(gA + (size_t)c * 32 * KX + (k0), (char*)lds + (s) * 32768 + c * 4096 + w * 1024);        \
            gld16(gB + (size_t)c * 32 * KX + (k0), (char*)lds + (s) * 32768 + 16384 + c * 4096 + w * 1024);\
        }

    // K=64 chunk = 4 slices of K=16; per slice this lane reads segment
    // sg = kk*2 + hi (k-bytes [sg*8, sg*8+8)), rows/cols = l31 within 32-block.
    #define MG_COMPUTE(s)                                                            \
        {                                                                            \
            const int ao = (s) * 16384, bo = (s) * 16384 + 8192;                     \
            _Pragma("unroll")                                                        \
            for (int kk = 0; kk < 4; ++kk) {                                         \
                const int sg = kk * 2 + hi;                                          \
                bf16x8 a2[2], b2[2];                                                 \
                _Pragma("unroll")                                                    \
                for (int i = 0; i < 2; ++i) {                                        \
                    const int ra = wm + i * 32 + l31;                                \
                    a2[i] = *(const bf16x8*)&lds[ao + ra * 64 + ((sg ^ (ra & 7)) * 8)]; \
                }                                                                    \
                _Pragma("unroll")                                                    \
                for (int j = 0; j < 2; ++j) {                                        \
                    const int rb = wn + j * 32 + l31;                                \
                    b2[j] = *(const bf16x8*)&lds[bo + rb * 64 + ((sg ^ (rb & 7)) * 8)]; \
                }                                                                    \
                _Pragma("unroll")                                                    \
                for (int i = 0; i < 2; ++i)                                          \
                    _Pragma("unroll")                                                \
                    for (int j = 0; j < 2; ++j)                                      \
                        acc[i][j] = __builtin_amdgcn_mfma_f32_32x32x16_bf16(a2[i], b2[j], acc[i][j], 0, 0, 0); \
            }                                                                        \
        }

    MG_STAGE(0, 0);
    for (int k0 = 0; k0 < KX; k0 += 128) {       // 9 macro-iters (18 chunks)
        __syncthreads();
        MG_STAGE(k0 + 64, 1);                    // k0+64 <= 1088 < 1152 always
        MG_COMPUTE(0);
        __syncthreads();
        if (k0 + 128 < KX) { MG_STAGE(k0 + 128, 0); }
        MG_COMPUTE(1);
    }
    #undef MG_STAGE
    #undef MG_COMPUTE

    // Epilogue: per-wave 64x64 LDS transpose -> coalesced float4 stores.
    // Write side uses the 32x32 C/D mapping; read side identical to R0.
    __syncthreads();
    float* lf = (float*)lds + w * 4096;
    #pragma unroll
    for (int j = 0; j < 2; ++j) {
        const float bv = bias[bn * 128 + wn + j * 32 + l31];
        #pragma unroll
        for (int i = 0; i < 2; ++i)
            #pragma unroll
            for (int r = 0; r < 16; ++r) {
                const int row_l = i * 32 + (r & 3) + 8 * (r >> 2) + 4 * hi;
                const int col   = j * 32 + l31;
                const int col_s = col ^ ((row_l & 1) << 4);
                lf[row_l * 64 + col_s] = acc[i][j][r] + bv;
            }
    }
    __builtin_amdgcn_s_waitcnt(0);
    #pragma unroll
    for (int rr = 0; rr < 16; ++rr) {
        const int row_r = rr * 4 + (lane >> 4);
        const int col4  = (lane & 15) * 4;
        const int col4s = col4 ^ ((row_r & 1) << 4);
        float4 vv = *(const float4*)&lf[row_r * 64 + col4s];
        *(float4*)&out[(size_t)(bm * 128 + wm + row_r) * DM + bn * 128 + wn + col4] = vv;
    }
}

// ---------------------------------------------------------------------------
extern "C" void kernel_launch(void* const* d_in, const int* in_sizes, int n_in,
                              void* d_out, int out_size, void* d_ws, size_t ws_size,
                              hipStream_t stream) {
    const float* x  = (const float*)d_in[0];   // [8192,1024]
    const float* Wg = (const float*)d_in[1];   // [8,1024]
    const float* A  = (const float*)d_in[2];   // [8,1024,16]
    const float* B  = (const float*)d_in[3];   // [8,16,1024]
    const float* Wb = (const float*)d_in[4];   // [1024,1024]
    const float* bb = (const float*)d_in[5];   // [1024]
    float* out = (float*)d_out;

    char* ws = (char*)d_ws;
    float*          combine = (float*)ws;                                   // 262144 B
    unsigned short* Xext    = (unsigned short*)(ws + 262144);               // 18874368 B
    unsigned short* WBext   = (unsigned short*)(ws + 262144 + 18874368);    // 2359296 B
    unsigned short* At      = (unsigned short*)(ws + 262144 + 18874368 + 2359296); // 262144 B

    hipLaunchKernelGGL(prep,        dim3(3200), dim3(256), 0, stream,
                       x, Wg, A, B, Wb, combine, Xext, WBext, At);
    hipLaunchKernelGGL(hall_kernel, dim3(512),  dim3(256), 0, stream, Xext, At, combine);
    hipLaunchKernelGGL(mgemm,       dim3(512),  dim3(256), 0, stream, Xext, WBext, bb, out);
}

// Round 6
// 127.977 us; speedup vs baseline: 1.0480x; 1.0361x over previous
//
#include <hip/hip_runtime.h>
#include <stdint.h>

// Problem constants (fixed by reference)
#define NTOK 8192
#define DM   1024
#define NE   8
#define NR   16
#define KX   1152   // DM + NE*NR = 1024 + 128

typedef short bf16x8 __attribute__((ext_vector_type(8)));
typedef float f32x4  __attribute__((ext_vector_type(4)));

__device__ __forceinline__ unsigned short f2bf(float f) {
    union { float f; unsigned u; } v; v.f = f;
    unsigned r = v.u + 0x7fffu + ((v.u >> 16) & 1u);   // RNE
    return (unsigned short)(r >> 16);
}

__device__ __forceinline__ void gld16(const void* g, void* l) {
    __builtin_amdgcn_global_load_lds((__attribute__((address_space(1))) void*)g,
                                     (__attribute__((address_space(3))) void*)l,
                                     16, 0, 0);
}

// ---------------------------------------------------------------------------
// prep: fused role-by-block kernel (R0-proven 128.5us configuration).
//  blocks [0,2048):     fp32 gating (wave/token) + x -> bf16 into Xext[:,0:1024]
//  blocks [2048,3072):  WBext[j][0:1152] = [W_base[j][:] | B[:, j]]  (bf16)
//  blocks [3072,3200):  At[p][0:1024] = A[e][:][r] transpose        (bf16)
// ---------------------------------------------------------------------------
__global__ __launch_bounds__(256) void prep(const float* __restrict__ x,
                                            const float* __restrict__ Wg,
                                            const float* __restrict__ Asrc,
                                            const float* __restrict__ Bsrc,
                                            const float* __restrict__ Wb,
                                            float* __restrict__ combine,
                                            unsigned short* __restrict__ Xext,
                                            unsigned short* __restrict__ WBext,
                                            unsigned short* __restrict__ At) {
    const int b = blockIdx.x;
    const int t = threadIdx.x;

    if (b < 2048) {
        const int lane = t & 63;
        const int w = t >> 6;
        const int n = b * 4 + w;

        const float4* x4 = (const float4*)(x + (size_t)n * DM);
        float4 xv[4];
        #pragma unroll
        for (int i = 0; i < 4; ++i) xv[i] = x4[i * 64 + lane];

        float acc[NE];
        #pragma unroll
        for (int e = 0; e < NE; ++e) {
            const float4* wg4 = (const float4*)(Wg + (size_t)e * DM);
            float s = 0.f;
            #pragma unroll
            for (int i = 0; i < 4; ++i) {
                float4 g = wg4[i * 64 + lane];
                s += xv[i].x * g.x + xv[i].y * g.y + xv[i].z * g.z + xv[i].w * g.w;
            }
            acc[e] = s;
        }
        #pragma unroll
        for (int off = 32; off >= 1; off >>= 1) {
            #pragma unroll
            for (int e = 0; e < NE; ++e) acc[e] += __shfl_xor(acc[e], off, 64);
        }
        // top-2, lowest index wins ties (matches lax.top_k)
        float best = acc[0]; int bi = 0;
        #pragma unroll
        for (int e = 1; e < NE; ++e) if (acc[e] > best) { best = acc[e]; bi = e; }
        float sec = -1e30f; int si = 0;
        #pragma unroll
        for (int e = 0; e < NE; ++e) if (e != bi && acc[e] > sec) { sec = acc[e]; si = e; }
        const float ed = __expf(sec - best);
        const float w0 = 1.f / (1.f + ed);
        const float w1 = ed * w0;
        if (lane < NE)
            combine[n * NE + lane] = (lane == bi) ? w0 : ((lane == si) ? w1 : 0.f);

        unsigned short* xrow = Xext + (size_t)n * KX;
        #pragma unroll
        for (int i = 0; i < 4; ++i) {
            ushort4 o;
            o.x = f2bf(xv[i].x); o.y = f2bf(xv[i].y);
            o.z = f2bf(xv[i].z); o.w = f2bf(xv[i].w);
            *(ushort4*)(xrow + (i * 64 + lane) * 4) = o;
        }
    } else if (b < 3072) {
        const int j = b - 2048;
        unsigned short* row = WBext + (size_t)j * KX;
        float4 v = ((const float4*)(Wb + (size_t)j * DM))[t];
        ushort4 o;
        o.x = f2bf(v.x); o.y = f2bf(v.y); o.z = f2bf(v.z); o.w = f2bf(v.w);
        *(ushort4*)(row + t * 4) = o;
        if (t < 128) row[DM + t] = f2bf(Bsrc[(size_t)t * DM + j]);   // B[e][r][j]
    } else {
        const int p = b - 3072;
        const int e = p >> 4, r = p & 15;
        for (int d = t; d < DM; d += 256)
            At[(size_t)p * DM + d] = f2bf(Asrc[e * (DM * NR) + d * NR + r]);
    }
}

// ---------------------------------------------------------------------------
// hall: Hfull = (x_bf16 @ At^T) * combine -> bf16 into Xext[:, 1024:1152]
//   512 blocks (32 tokens x 64 cols -> 2 blocks/CU), single-barrier
//   double-buffered K-loop: stage(k+1 -> other buf) issued right after the
//   barrier, compute(k) runs while loads are in flight; next barrier's
//   vmcnt(0) drain lands on loads a full compute-phase old.
// ---------------------------------------------------------------------------
__global__ __launch_bounds__(256) void hall_kernel(unsigned short* Xext,
                                                   const unsigned short* __restrict__ At,
                                                   const float* __restrict__ combine) {
    // per buffer: xt 32x64 bf16 (4 KB) + at 64x64 bf16 (8 KB) = 12 KB; x2 = 24 KB
    __shared__ __align__(16) unsigned short lds[12288];
    const int t = threadIdx.x;
    const int lane = t & 63;
    const int w = t >> 6;
    const int quad = lane >> 4;
    const int l15 = lane & 15;
    const int bid = blockIdx.x;        // 512
    const int bm = bid >> 1;           // token tile 0..255
    const int cb = bid & 1;            // column half 0..1
    const int n0 = bm * 32;
    const int wm = (w & 1) * 16;
    const int wn = (w >> 1) * 32;

    const int srow = t >> 3;                     // 0..31
    const int seg  = (t & 7) ^ (srow & 7);       // XOR swizzle (global side)

    const unsigned short* gX  = Xext + (size_t)(n0 + srow) * KX + seg * 8;
    const unsigned short* gA0 = At + (size_t)(cb * 64 + srow) * DM + seg * 8;
    const unsigned short* gA1 = At + (size_t)(cb * 64 + 32 + srow) * DM + seg * 8;

    f32x4 acc[2] = {};

    // stage(k0, buf s): x -> [s*12KB, +4KB), At -> [s*12KB+4KB, +8KB)
    #define HALL_STAGE(k0, s)                                              \
        gld16(gX  + (k0), (char*)lds + (s) * 12288 + w * 1024);            \
        gld16(gA0 + (k0), (char*)lds + (s) * 12288 + 4096 + w * 1024);     \
        gld16(gA1 + (k0), (char*)lds + (s) * 12288 + 8192 + w * 1024);

    #define HALL_COMPUTE(s)                                                        \
        {                                                                          \
            const int xo = (s) * 6144, ao = (s) * 6144 + 2048;                     \
            _Pragma("unroll")                                                      \
            for (int kk = 0; kk < 2; ++kk) {                                       \
                const int gs = kk * 4 + quad;                                      \
                const int sw = (gs ^ (l15 & 7)) * 8;                               \
                bf16x8 a = *(const bf16x8*)&lds[xo + (wm + l15) * 64 + sw];        \
                _Pragma("unroll")                                                  \
                for (int jf = 0; jf < 2; ++jf) {                                   \
                    bf16x8 bb = *(const bf16x8*)&lds[ao + (wn + jf * 16 + l15) * 64 + sw]; \
                    acc[jf] = __builtin_amdgcn_mfma_f32_16x16x32_bf16(a, bb, acc[jf], 0, 0, 0); \
                }                                                                  \
            }                                                                      \
        }

    HALL_STAGE(0, 0);
    for (int k0 = 0; k0 < DM; k0 += 128) {       // 8 macro-iters (16 chunks)
        __syncthreads();
        HALL_STAGE(k0 + 64, 1);                  // k0+64 <= 960+64 = 1024? guard:
        HALL_COMPUTE(0);
        __syncthreads();
        if (k0 + 128 < DM) { HALL_STAGE(k0 + 128, 0); }
        HALL_COMPUTE(1);
    }
    // NOTE: at k0 = DM-128 the first stage targets k0+64 = DM-64 (valid).

    // Epilogue: scale by combine, write bf16 H
    #pragma unroll
    for (int jf = 0; jf < 2; ++jf) {
        const int p = cb * 64 + wn + jf * 16 + l15;
        const int e = p >> 4;
        #pragma unroll
        for (int v = 0; v < 4; ++v) {
            const int n = n0 + wm + quad * 4 + v;
            const float val = acc[jf][v] * combine[n * NE + e];
            Xext[(size_t)n * KX + DM + p] = f2bf(val);
        }
    }
    #undef HALL_STAGE
    #undef HALL_COMPUTE
}

// ---------------------------------------------------------------------------
// mgemm: out[8192][1024] = Xext[8192][1152] @ WBext[1024][1152]^T + bias
//   128x128 tile, BK=64 double-buffered (A0|B0|A1|B1 = 4x16 KB = 64 KB),
//   SINGLE barrier per K-chunk: stage(k+1) issued post-barrier, compute(k)
//   hides the load latency. XOR-swizzled K-segments, LDS-transpose epilogue,
//   XCD-aware block decode.  (exact R0 128.5us configuration)
// ---------------------------------------------------------------------------
__global__ __launch_bounds__(256, 2) void mgemm(const unsigned short* __restrict__ Xext,
                                                const unsigned short* __restrict__ WBext,
                                                const float* __restrict__ bias,
                                                float* __restrict__ out) {
    __shared__ __align__(16) unsigned short lds[32768];   // 64 KB
    const int t = threadIdx.x;
    const int lane = t & 63;
    const int w = t >> 6;
    const int quad = lane >> 4;
    const int l15 = lane & 15;

    const int bid = blockIdx.x;          // 512
    const int xcd = bid & 7;
    const int loc = bid >> 3;
    const int bm = xcd * 8 + (loc & 7);  // 0..63
    const int bn = loc >> 3;             // 0..7

    const int wm = (w & 1) * 64;
    const int wn = (w >> 1) * 64;

    f32x4 acc[4][4] = {};

    const int srow = t >> 3;                     // 0..31
    const int seg  = (t & 7) ^ (srow & 7);       // XOR swizzle (global side)
    const unsigned short* gA = Xext  + (size_t)(bm * 128 + srow) * KX + seg * 8;
    const unsigned short* gB = WBext + (size_t)(bn * 128 + srow) * KX + seg * 8;

    #define MG_STAGE(k0, s)                                                          \
        _Pragma("unroll")                                                            \
        for (int c = 0; c < 4; ++c) {                                                \
            gld16(gA + (size_t)c * 32 * KX + (k0), (char*)lds + (s) * 32768 + c * 4096 + w * 1024);        \
            gld16(gB + (size_t)c * 32 * KX + (k0), (char*)lds + (s) * 32768 + 16384 + c * 4096 + w * 1024);\
        }

    #define MG_COMPUTE(s)                                                            \
        {                                                                            \
            const int ao = (s) * 16384, bo = (s) * 16384 + 8192;                     \
            _Pragma("unroll")                                                        \
            for (int kk = 0; kk < 2; ++kk) {                                         \
                const int gs = kk * 4 + quad;                                        \
                const int sw = (gs ^ (l15 & 7)) * 8;                                 \
                bf16x8 a[4], b[4];                                                   \
                _Pragma("unroll")                                                    \
                for (int i = 0; i < 4; ++i)                                          \
                    a[i] = *(const bf16x8*)&lds[ao + (wm + i * 16 + l15) * 64 + sw]; \
                _Pragma("unroll")                                                    \
                for (int j = 0; j < 4; ++j)                                          \
                    b[j] = *(const bf16x8*)&lds[bo + (wn + j * 16 + l15) * 64 + sw]; \
                _Pragma("unroll")                                                    \
                for (int i = 0; i < 4; ++i)                                          \
                    _Pragma("unroll")                                                \
                    for (int j = 0; j < 4; ++j)                                      \
                        acc[i][j] = __builtin_amdgcn_mfma_f32_16x16x32_bf16(a[i], b[j], acc[i][j], 0, 0, 0); \
            }                                                                        \
        }

    MG_STAGE(0, 0);
    for (int k0 = 0; k0 < KX; k0 += 128) {       // 9 macro-iters (18 chunks)
        __syncthreads();
        MG_STAGE(k0 + 64, 1);                    // k0+64 <= 1088 < 1152 always
        MG_COMPUTE(0);
        __syncthreads();
        if (k0 + 128 < KX) { MG_STAGE(k0 + 128, 0); }
        MG_COMPUTE(1);
    }
    #undef MG_STAGE
    #undef MG_COMPUTE

    // Epilogue: per-wave 64x64 LDS transpose -> coalesced float4 stores
    __syncthreads();
    float* lf = (float*)lds + w * 4096;
    #pragma unroll
    for (int j = 0; j < 4; ++j) {
        const float bv = bias[bn * 128 + wn + j * 16 + l15];
        #pragma unroll
        for (int i = 0; i < 4; ++i)
            #pragma unroll
            for (int v = 0; v < 4; ++v) {
                const int row_l = i * 16 + quad * 4 + v;
                const int col_s = (j * 16 + l15) ^ ((row_l & 1) << 4);
                lf[row_l * 64 + col_s] = acc[i][j][v] + bv;
            }
    }
    __builtin_amdgcn_s_waitcnt(0);
    #pragma unroll
    for (int rr = 0; rr < 16; ++rr) {
        const int row_r = rr * 4 + (lane >> 4);
        const int col4  = (lane & 15) * 4;
        const int col4s = col4 ^ ((row_r & 1) << 4);
        float4 vv = *(const float4*)&lf[row_r * 64 + col4s];
        *(float4*)&out[(size_t)(bm * 128 + wm + row_r) * DM + bn * 128 + wn + col4] = vv;
    }
}

// ---------------------------------------------------------------------------
extern "C" void kernel_launch(void* const* d_in, const int* in_sizes, int n_in,
                              void* d_out, int out_size, void* d_ws, size_t ws_size,
                              hipStream_t stream) {
    const float* x  = (const float*)d_in[0];   // [8192,1024]
    const float* Wg = (const float*)d_in[1];   // [8,1024]
    const float* A  = (const float*)d_in[2];   // [8,1024,16]
    const float* B  = (const float*)d_in[3];   // [8,16,1024]
    const float* Wb = (const float*)d_in[4];   // [1024,1024]
    const float* bb = (const float*)d_in[5];   // [1024]
    float* out = (float*)d_out;

    char* ws = (char*)d_ws;
    float*          combine = (float*)ws;                                   // 262144 B
    unsigned short* Xext    = (unsigned short*)(ws + 262144);               // 18874368 B
    unsigned short* WBext   = (unsigned short*)(ws + 262144 + 18874368);    // 2359296 B
    unsigned short* At      = (unsigned short*)(ws + 262144 + 18874368 + 2359296); // 262144 B

    hipLaunchKernelGGL(prep,        dim3(3200), dim3(256), 0, stream,
                       x, Wg, A, B, Wb, combine, Xext, WBext, At);
    hipLaunchKernelGGL(hall_kernel, dim3(512),  dim3(256), 0, stream, Xext, At, combine);
    hipLaunchKernelGGL(mgemm,       dim3(512),  dim3(256), 0, stream, Xext, WBext, bb, out);
}